// Round 6
// baseline (249.016 us; speedup 1.0000x reference)
//
#include <hip/hip_runtime.h>
#include <hip/hip_bf16.h>

#define N_TOT 65536
#define M_TOT 32768

typedef __bf16 bf16x8 __attribute__((ext_vector_type(8)));
typedef float  f32x4  __attribute__((ext_vector_type(4)));
typedef bf16x8 bf16x8_a __attribute__((may_alias));
typedef uint2  uint2_a  __attribute__((may_alias));

__device__ __forceinline__ float prelu_f(float x, float a) { return x >= 0.f ? x : a * x; }
// swizzle: uniform bank spread for stage-2 writes (row=4*j15+c) and
// stage-3 reads (row=16t+j15). XORs LDS 16B-slot index with ((row^(row>>3))&7).
__device__ __forceinline__ int swzf(int row) { return ((row ^ (row >> 3)) & 7) << 4; }

__device__ __forceinline__ bf16x8 cvt8(f32x4 a, f32x4 b) {
    bf16x8 v;
    v[0] = (__bf16)a[0]; v[1] = (__bf16)a[1]; v[2] = (__bf16)a[2]; v[3] = (__bf16)a[3];
    v[4] = (__bf16)b[0]; v[5] = (__bf16)b[1]; v[6] = (__bf16)b[2]; v[7] = (__bf16)b[3];
    return v;
}

#define MFMA(A, B, C) __builtin_amdgcn_mfma_f32_16x16x32_bf16((A), (B), (C), 0, 0, 0)

// d_ws layout (bf16): [0,8192) Wm_t[64][128]; [8192,40960) Wms_t[256][128];
// [40960,49152) Wsa_t[64][128].  W*_t[n][k] = W[k][n].
__global__ void prep_weights(const float* __restrict__ Wm,
                             const float* __restrict__ Wms,
                             const float* __restrict__ Wsa,
                             __hip_bfloat16* __restrict__ ws)
{
    int t = blockIdx.x * blockDim.x + threadIdx.x;
    if (t < 8192) {
        int n = t >> 7, k = t & 127;
        ws[t] = __float2bfloat16(Wm[k * 64 + n]);
    } else if (t < 40960) {
        int u = t - 8192; int n = u >> 7, k = u & 127;
        ws[t] = __float2bfloat16(Wms[k * 256 + n]);
    } else if (t < 49152) {
        int u = t - 40960; int n = u >> 7, k = u & 127;
        ws[t] = __float2bfloat16(Wsa[k * 64 + n]);
    }
}

// One wave = 16 nodes, fused stage1/2/3. s' via 8KB/wave LDS; ans via 4-lane
// XOR shuffles. Swapped MFMA: D = W^T X^T.
// Memory-access pattern deliberately matches R1 (VGPR 92, zero scratch):
// loads -> convert -> consume locally inside constant-trip unrolled loops;
// NO register arrays held across large code spans (R2/R3's gr[2][8]/sr[8]
// were demoted to scratch: VGPR 56, +64MB spill writes).
__global__ __launch_bounds__(256, 2) void encoder_fused(
    const float* __restrict__ last,
    const float* __restrict__ sample,
    const int* __restrict__ child_l,
    const int* __restrict__ child_r,
    const int* __restrict__ child_s,
    const __bf16* __restrict__ wt,
    const float* __restrict__ b_merge, const float* __restrict__ a_merge_p,
    const float* __restrict__ b_ms,    const float* __restrict__ a_ms_p,
    const float* __restrict__ b_msamp, const float* __restrict__ a_msamp_p,
    float* __restrict__ out)
{
    __shared__ char lds_raw[4][8192];       // 32KB/block
    const int tid  = threadIdx.x;
    const int lane = tid & 63;
    const int wid  = tid >> 6;
    char* Y = &lds_raw[wid][0];             // wave-private [64 rows][128B]

    const int group  = blockIdx.x * 4 + wid;
    const int b      = group >> 11;
    const int m_base = (group & 2047) << 4;

    const int g   = lane >> 4;
    const int j15 = lane & 15;
    const int nl  = j15 >> 2;
    const int c   = j15 & 3;

    const float a_merge = *a_merge_p;
    const float a_ms    = *a_ms_p;
    const float a_msamp = *a_msamp_p;

    const __bf16* Wm_t  = wt;
    const __bf16* Wms_t = wt + 8192;
    const __bf16* Wsa_t = wt + 40960;

    // ---- stage 2: s' = prelu(s @ W_ms + b_ms) -> LDS ----
    {
        const int cs = child_s[m_base + j15];
        const float* ssrc = sample + ((size_t)(b * N_TOT + cs)) * 128;
        bf16x8 sf[4];
#pragma unroll
        for (int kk = 0; kk < 4; ++kk) {
            f32x4 f0 = *(const f32x4*)(ssrc + kk * 32 + g * 8);
            f32x4 f1 = *(const f32x4*)(ssrc + kk * 32 + g * 8 + 4);
            sf[kk] = cvt8(f0, f1);
        }
#pragma unroll
        for (int n2 = 0; n2 < 16; ++n2) {
            f32x4 acc = {0.f, 0.f, 0.f, 0.f};
#pragma unroll
            for (int kk = 0; kk < 4; ++kk) {
                bf16x8 w = *(const bf16x8*)(Wms_t + (n2 * 16 + j15) * 128 + kk * 32 + g * 8);
                acc = MFMA(w, sf[kk], acc);
            }
            f32x4 bb = *(const f32x4*)(b_ms + n2 * 16 + g * 4);
            union { __bf16 h[4]; uint2 u2; } p;
            p.h[0] = (__bf16)prelu_f(acc[0] + bb[0], a_ms);
            p.h[1] = (__bf16)prelu_f(acc[1] + bb[1], a_ms);
            p.h[2] = (__bf16)prelu_f(acc[2] + bb[2], a_ms);
            p.h[3] = (__bf16)prelu_f(acc[3] + bb[3], a_ms);
            const int row = j15 * 4 + (n2 >> 2);          // node j15, c = n2>>2
            const int d   = (n2 & 3) * 16 + g * 4;        // within-c feature
            *(uint2_a*)(Y + row * 128 + ((2 * d) ^ swzf(row))) = p.u2;
        }
    }

    // ---- fused stage 1 + exchange + stage 3, per t (R1-style in-loop loads) ----
#pragma unroll
    for (int t = 0; t < 4; ++t) {
        const int m  = m_base + t * 4 + nl;
        const int cl = child_l[m];
        const int cr = child_r[m];
        const float* lsrc = last + ((size_t)((b * N_TOT + cl) * 4 + c)) * 64;
        const float* rsrc = last + ((size_t)((b * N_TOT + cr) * 4 + c)) * 64;

        bf16x8 xf[4];
#pragma unroll
        for (int kk = 0; kk < 4; ++kk) {
            const int k = kk * 32 + g * 8;       // k<64 -> lch, else rch
            const float* src = (k < 64) ? (lsrc + k) : (rsrc + (k - 64));
            f32x4 f0 = *(const f32x4*)(src);
            f32x4 f1 = *(const f32x4*)(src + 4);
            xf[kk] = cvt8(f0, f1);
        }

        // stage-1 MFMA: lane (g,j15) produces ans chunk q=4n+g (4 feats), row 16t+j15
        uint32_t pnx[4], pny[4];
#pragma unroll
        for (int n = 0; n < 4; ++n) {
            f32x4 acc = {0.f, 0.f, 0.f, 0.f};
#pragma unroll
            for (int kk = 0; kk < 4; ++kk) {
                bf16x8 w = *(const bf16x8*)(Wm_t + (n * 16 + j15) * 128 + kk * 32 + g * 8);
                acc = MFMA(w, xf[kk], acc);
            }
            f32x4 bm = *(const f32x4*)(b_merge + n * 16 + g * 4);
            union { __bf16 h[4]; uint32_t u[2]; } p;
            p.h[0] = (__bf16)prelu_f(acc[0] + bm[0], a_merge);
            p.h[1] = (__bf16)prelu_f(acc[1] + bm[1], a_merge);
            p.h[2] = (__bf16)prelu_f(acc[2] + bm[2], a_merge);
            p.h[3] = (__bf16)prelu_f(acc[3] + bm[3], a_merge);
            pnx[n] = p.u[0]; pny[n] = p.u[1];
        }

        // exchange ans across the 4 g-lanes (lane bits 4-5) via XOR shuffles
        const int dlo = (4 - g) & 3;
        const int dhi = dlo ^ 1;
        uint32_t lox[2], loy[2], hix[2], hiy[2];
#pragma unroll
        for (int d = 0; d < 4; ++d) {
            const int nsbit = ((g ^ d) >> 1) & 1;
#pragma unroll
            for (int kk = 0; kk < 2; ++kk) {
                uint32_t vx = nsbit ? pnx[2 * kk + 1] : pnx[2 * kk];
                uint32_t vy = nsbit ? pny[2 * kk + 1] : pny[2 * kk];
                uint32_t rx = d ? __shfl_xor(vx, d << 4, 64) : vx;
                uint32_t ry = d ? __shfl_xor(vy, d << 4, 64) : vy;
                if (d == 0) {
                    lox[kk] = rx; loy[kk] = ry; hix[kk] = rx; hiy[kk] = ry;
                } else {
                    lox[kk] = (dlo == d) ? rx : lox[kk];
                    loy[kk] = (dlo == d) ? ry : loy[kk];
                    hix[kk] = (dhi == d) ? rx : hix[kk];
                    hiy[kk] = (dhi == d) ? ry : hiy[kk];
                }
            }
        }
        union { uint32_t u[4]; bf16x8_a v; } yf0, yf1;
        yf0.u[0] = lox[0]; yf0.u[1] = loy[0]; yf0.u[2] = hix[0]; yf0.u[3] = hiy[0];
        yf1.u[0] = lox[1]; yf1.u[1] = loy[1]; yf1.u[2] = hix[1]; yf1.u[3] = hiy[1];

        // s' fragments from LDS
        const int row = t * 16 + j15;
        const int sz  = swzf(row);
        bf16x8 yf2 = *(const bf16x8_a*)(Y + row * 128 + ((16 * g) ^ sz));
        bf16x8 yf3 = *(const bf16x8_a*)(Y + row * 128 + ((64 + 16 * g) ^ sz));

        // stage 3: out = prelu([ans|s'] @ W_msamp + b_msamp)
        float* obase = out + ((size_t)((b * M_TOT + m_base + t * 4 + nl) * 4 + c)) * 64;
#pragma unroll
        for (int n = 0; n < 4; ++n) {
            f32x4 acc = {0.f, 0.f, 0.f, 0.f};
            bf16x8 w0 = *(const bf16x8*)(Wsa_t + (n * 16 + j15) * 128 + 0 * 32 + g * 8);
            bf16x8 w1 = *(const bf16x8*)(Wsa_t + (n * 16 + j15) * 128 + 1 * 32 + g * 8);
            bf16x8 w2 = *(const bf16x8*)(Wsa_t + (n * 16 + j15) * 128 + 2 * 32 + g * 8);
            bf16x8 w3 = *(const bf16x8*)(Wsa_t + (n * 16 + j15) * 128 + 3 * 32 + g * 8);
            acc = MFMA(w0, yf0.v, acc);
            acc = MFMA(w1, yf1.v, acc);
            acc = MFMA(w2, yf2,   acc);
            acc = MFMA(w3, yf3,   acc);
            f32x4 ba = *(const f32x4*)(b_msamp + n * 16 + g * 4);
            f32x4 o;
            o[0] = prelu_f(acc[0] + ba[0], a_msamp);
            o[1] = prelu_f(acc[1] + ba[1], a_msamp);
            o[2] = prelu_f(acc[2] + ba[2], a_msamp);
            o[3] = prelu_f(acc[3] + ba[3], a_msamp);
            // streamed output, never re-read: non-temporal to keep L2/L3 for gathers
            __builtin_nontemporal_store(o, (f32x4*)(obase + n * 16 + g * 4));
        }
    }
}

extern "C" void kernel_launch(void* const* d_in, const int* in_sizes, int n_in,
                              void* d_out, int out_size, void* d_ws, size_t ws_size,
                              hipStream_t stream)
{
    const float* last    = (const float*)d_in[0];
    const float* sample  = (const float*)d_in[1];
    const int*   child_l = (const int*)d_in[2];
    const int*   child_r = (const int*)d_in[3];
    const int*   child_s = (const int*)d_in[4];
    const float* W_merge = (const float*)d_in[5];
    const float* b_merge = (const float*)d_in[6];
    const float* a_merge = (const float*)d_in[7];
    const float* W_ms    = (const float*)d_in[8];
    const float* b_ms    = (const float*)d_in[9];
    const float* a_ms    = (const float*)d_in[10];
    const float* W_msamp = (const float*)d_in[11];
    const float* b_msamp = (const float*)d_in[12];
    const float* a_msamp = (const float*)d_in[13];
    float* out = (float*)d_out;

    hipLaunchKernelGGL(prep_weights, dim3(192), dim3(256), 0, stream,
                       W_merge, W_ms, W_msamp, (__hip_bfloat16*)d_ws);

    hipLaunchKernelGGL(encoder_fused, dim3(2048), dim3(256), 0, stream,
                       last, sample, child_l, child_r, child_s,
                       (const __bf16*)d_ws,
                       b_merge, a_merge, b_ms, a_ms, b_msamp, a_msamp, out);
}

// Round 7
// 247.983 us; speedup vs baseline: 1.0042x; 1.0042x over previous
//
#include <hip/hip_runtime.h>
#include <hip/hip_bf16.h>

#define N_TOT 65536
#define M_TOT 32768

typedef __bf16  bf16x8 __attribute__((ext_vector_type(8)));
typedef __bf16  bf16x4 __attribute__((ext_vector_type(4)));
typedef float   f32x4  __attribute__((ext_vector_type(4)));
typedef uint32_t u32x2 __attribute__((ext_vector_type(2)));
typedef uint32_t u32x4 __attribute__((ext_vector_type(4)));
typedef bf16x8 bf16x8_a __attribute__((may_alias));
typedef u32x2  u32x2_a  __attribute__((may_alias));

__device__ __forceinline__ float prelu_f(float x, float a) { return x >= 0.f ? x : a * x; }
// swizzle: uniform bank spread for stage-2 writes (row=4*j15+c) and
// stage-3 reads (row=16t+j15). XORs LDS 16B-slot index with ((row^(row>>3))&7).
__device__ __forceinline__ int swzf(int row) { return ((row ^ (row >> 3)) & 7) << 4; }

__device__ __forceinline__ bf16x8 cvt8(f32x4 a, f32x4 b) {
    bf16x8 v;
    v[0] = (__bf16)a[0]; v[1] = (__bf16)a[1]; v[2] = (__bf16)a[2]; v[3] = (__bf16)a[3];
    v[4] = (__bf16)b[0]; v[5] = (__bf16)b[1]; v[6] = (__bf16)b[2]; v[7] = (__bf16)b[3];
    return v;
}

#define MFMA(A, B, C) __builtin_amdgcn_mfma_f32_16x16x32_bf16((A), (B), (C), 0, 0, 0)

// d_ws layout (bf16): [0,8192) Wm_t[64][128]; [8192,40960) Wms_t[256][128];
// [40960,49152) Wsa_t[64][128].  W*_t[n][k] = W[k][n].
__global__ void prep_weights(const float* __restrict__ Wm,
                             const float* __restrict__ Wms,
                             const float* __restrict__ Wsa,
                             __hip_bfloat16* __restrict__ ws)
{
    int t = blockIdx.x * blockDim.x + threadIdx.x;
    if (t < 8192) {
        int n = t >> 7, k = t & 127;
        ws[t] = __float2bfloat16(Wm[k * 64 + n]);
    } else if (t < 40960) {
        int u = t - 8192; int n = u >> 7, k = u & 127;
        ws[t] = __float2bfloat16(Wms[k * 256 + n]);
    } else if (t < 49152) {
        int u = t - 40960; int n = u >> 7, k = u & 127;
        ws[t] = __float2bfloat16(Wsa[k * 64 + n]);
    }
}

// One wave = 16 nodes, fused stage1/2/3. s' via 8KB/wave LDS; ans via 4-lane
// XOR shuffles. Swapped MFMA: D = W^T X^T.
// R7 delta vs R6 (passing): ALL union-based type punning replaced with
// ext_vector inserts + __builtin_bit_cast. Unions always lower to an alloca
// and rely on SROA; the {u32[4]; may_alias-vector} unions introduced in R2
// never got promoted -> whole frame in scratch (VGPR 44-56, +70MB spill
// writes in R2/R3/R6). Vector insertelement is pure SSA: no alloca exists.
__global__ __launch_bounds__(256, 2) void encoder_fused(
    const float* __restrict__ last,
    const float* __restrict__ sample,
    const int* __restrict__ child_l,
    const int* __restrict__ child_r,
    const int* __restrict__ child_s,
    const __bf16* __restrict__ wt,
    const float* __restrict__ b_merge, const float* __restrict__ a_merge_p,
    const float* __restrict__ b_ms,    const float* __restrict__ a_ms_p,
    const float* __restrict__ b_msamp, const float* __restrict__ a_msamp_p,
    float* __restrict__ out)
{
    __shared__ char lds_raw[4][8192];       // 32KB/block
    const int tid  = threadIdx.x;
    const int lane = tid & 63;
    const int wid  = tid >> 6;
    char* Y = &lds_raw[wid][0];             // wave-private [64 rows][128B]

    const int group  = blockIdx.x * 4 + wid;
    const int b      = group >> 11;
    const int m_base = (group & 2047) << 4;

    const int g   = lane >> 4;
    const int j15 = lane & 15;
    const int nl  = j15 >> 2;
    const int c   = j15 & 3;

    const float a_merge = *a_merge_p;
    const float a_ms    = *a_ms_p;
    const float a_msamp = *a_msamp_p;

    const __bf16* Wm_t  = wt;
    const __bf16* Wms_t = wt + 8192;
    const __bf16* Wsa_t = wt + 40960;

    // ---- stage 2: s' = prelu(s @ W_ms + b_ms) -> LDS ----
    {
        const int cs = child_s[m_base + j15];
        const float* ssrc = sample + ((size_t)(b * N_TOT + cs)) * 128;
        bf16x8 sf[4];
#pragma unroll
        for (int kk = 0; kk < 4; ++kk) {
            f32x4 f0 = *(const f32x4*)(ssrc + kk * 32 + g * 8);
            f32x4 f1 = *(const f32x4*)(ssrc + kk * 32 + g * 8 + 4);
            sf[kk] = cvt8(f0, f1);
        }
#pragma unroll
        for (int n2 = 0; n2 < 16; ++n2) {
            f32x4 acc = {0.f, 0.f, 0.f, 0.f};
#pragma unroll
            for (int kk = 0; kk < 4; ++kk) {
                bf16x8 w = *(const bf16x8*)(Wms_t + (n2 * 16 + j15) * 128 + kk * 32 + g * 8);
                acc = MFMA(w, sf[kk], acc);
            }
            f32x4 bb = *(const f32x4*)(b_ms + n2 * 16 + g * 4);
            bf16x4 ph;
            ph[0] = (__bf16)prelu_f(acc[0] + bb[0], a_ms);
            ph[1] = (__bf16)prelu_f(acc[1] + bb[1], a_ms);
            ph[2] = (__bf16)prelu_f(acc[2] + bb[2], a_ms);
            ph[3] = (__bf16)prelu_f(acc[3] + bb[3], a_ms);
            const int row = j15 * 4 + (n2 >> 2);          // node j15, c = n2>>2
            const int d   = (n2 & 3) * 16 + g * 4;        // within-c feature
            *(u32x2_a*)(Y + row * 128 + ((2 * d) ^ swzf(row))) = __builtin_bit_cast(u32x2, ph);
        }
    }

    // ---- fused stage 1 + exchange + stage 3, per t (R1-style in-loop loads) ----
#pragma unroll
    for (int t = 0; t < 4; ++t) {
        const int m  = m_base + t * 4 + nl;
        const int cl = child_l[m];
        const int cr = child_r[m];
        const float* lsrc = last + ((size_t)((b * N_TOT + cl) * 4 + c)) * 64;
        const float* rsrc = last + ((size_t)((b * N_TOT + cr) * 4 + c)) * 64;

        bf16x8 xf[4];
#pragma unroll
        for (int kk = 0; kk < 4; ++kk) {
            const int k = kk * 32 + g * 8;       // k<64 -> lch, else rch
            const float* src = (k < 64) ? (lsrc + k) : (rsrc + (k - 64));
            f32x4 f0 = *(const f32x4*)(src);
            f32x4 f1 = *(const f32x4*)(src + 4);
            xf[kk] = cvt8(f0, f1);
        }

        // stage-1 MFMA: lane (g,j15) produces ans chunk q=4n+g (4 feats), row 16t+j15
        uint32_t pnx[4], pny[4];
#pragma unroll
        for (int n = 0; n < 4; ++n) {
            f32x4 acc = {0.f, 0.f, 0.f, 0.f};
#pragma unroll
            for (int kk = 0; kk < 4; ++kk) {
                bf16x8 w = *(const bf16x8*)(Wm_t + (n * 16 + j15) * 128 + kk * 32 + g * 8);
                acc = MFMA(w, xf[kk], acc);
            }
            f32x4 bm = *(const f32x4*)(b_merge + n * 16 + g * 4);
            bf16x4 ph;
            ph[0] = (__bf16)prelu_f(acc[0] + bm[0], a_merge);
            ph[1] = (__bf16)prelu_f(acc[1] + bm[1], a_merge);
            ph[2] = (__bf16)prelu_f(acc[2] + bm[2], a_merge);
            ph[3] = (__bf16)prelu_f(acc[3] + bm[3], a_merge);
            u32x2 pu = __builtin_bit_cast(u32x2, ph);
            pnx[n] = pu[0]; pny[n] = pu[1];
        }

        // exchange ans across the 4 g-lanes (lane bits 4-5) via XOR shuffles
        const int dlo = (4 - g) & 3;
        const int dhi = dlo ^ 1;
        uint32_t lox[2], loy[2], hix[2], hiy[2];
#pragma unroll
        for (int d = 0; d < 4; ++d) {
            const int nsbit = ((g ^ d) >> 1) & 1;
#pragma unroll
            for (int kk = 0; kk < 2; ++kk) {
                uint32_t vx = nsbit ? pnx[2 * kk + 1] : pnx[2 * kk];
                uint32_t vy = nsbit ? pny[2 * kk + 1] : pny[2 * kk];
                uint32_t rx = d ? __shfl_xor(vx, d << 4, 64) : vx;
                uint32_t ry = d ? __shfl_xor(vy, d << 4, 64) : vy;
                if (d == 0) {
                    lox[kk] = rx; loy[kk] = ry; hix[kk] = rx; hiy[kk] = ry;
                } else {
                    lox[kk] = (dlo == d) ? rx : lox[kk];
                    loy[kk] = (dlo == d) ? ry : loy[kk];
                    hix[kk] = (dhi == d) ? rx : hix[kk];
                    hiy[kk] = (dhi == d) ? ry : hiy[kk];
                }
            }
        }
        u32x4 y0u; y0u[0] = lox[0]; y0u[1] = loy[0]; y0u[2] = hix[0]; y0u[3] = hiy[0];
        u32x4 y1u; y1u[0] = lox[1]; y1u[1] = loy[1]; y1u[2] = hix[1]; y1u[3] = hiy[1];
        bf16x8 yf0 = __builtin_bit_cast(bf16x8, y0u);
        bf16x8 yf1 = __builtin_bit_cast(bf16x8, y1u);

        // s' fragments from LDS
        const int row = t * 16 + j15;
        const int sz  = swzf(row);
        bf16x8 yf2 = *(const bf16x8_a*)(Y + row * 128 + ((16 * g) ^ sz));
        bf16x8 yf3 = *(const bf16x8_a*)(Y + row * 128 + ((64 + 16 * g) ^ sz));

        // stage 3: out = prelu([ans|s'] @ W_msamp + b_msamp)
        float* obase = out + ((size_t)((b * M_TOT + m_base + t * 4 + nl) * 4 + c)) * 64;
#pragma unroll
        for (int n = 0; n < 4; ++n) {
            f32x4 acc = {0.f, 0.f, 0.f, 0.f};
            bf16x8 w0 = *(const bf16x8*)(Wsa_t + (n * 16 + j15) * 128 + 0 * 32 + g * 8);
            bf16x8 w1 = *(const bf16x8*)(Wsa_t + (n * 16 + j15) * 128 + 1 * 32 + g * 8);
            bf16x8 w2 = *(const bf16x8*)(Wsa_t + (n * 16 + j15) * 128 + 2 * 32 + g * 8);
            bf16x8 w3 = *(const bf16x8*)(Wsa_t + (n * 16 + j15) * 128 + 3 * 32 + g * 8);
            acc = MFMA(w0, yf0, acc);
            acc = MFMA(w1, yf1, acc);
            acc = MFMA(w2, yf2, acc);
            acc = MFMA(w3, yf3, acc);
            f32x4 ba = *(const f32x4*)(b_msamp + n * 16 + g * 4);
            f32x4 o;
            o[0] = prelu_f(acc[0] + ba[0], a_msamp);
            o[1] = prelu_f(acc[1] + ba[1], a_msamp);
            o[2] = prelu_f(acc[2] + ba[2], a_msamp);
            o[3] = prelu_f(acc[3] + ba[3], a_msamp);
            // streamed output, never re-read: non-temporal to keep L2/L3 for gathers
            __builtin_nontemporal_store(o, (f32x4*)(obase + n * 16 + g * 4));
        }
    }
}

extern "C" void kernel_launch(void* const* d_in, const int* in_sizes, int n_in,
                              void* d_out, int out_size, void* d_ws, size_t ws_size,
                              hipStream_t stream)
{
    const float* last    = (const float*)d_in[0];
    const float* sample  = (const float*)d_in[1];
    const int*   child_l = (const int*)d_in[2];
    const int*   child_r = (const int*)d_in[3];
    const int*   child_s = (const int*)d_in[4];
    const float* W_merge = (const float*)d_in[5];
    const float* b_merge = (const float*)d_in[6];
    const float* a_merge = (const float*)d_in[7];
    const float* W_ms    = (const float*)d_in[8];
    const float* b_ms    = (const float*)d_in[9];
    const float* a_ms    = (const float*)d_in[10];
    const float* W_msamp = (const float*)d_in[11];
    const float* b_msamp = (const float*)d_in[12];
    const float* a_msamp = (const float*)d_in[13];
    float* out = (float*)d_out;

    hipLaunchKernelGGL(prep_weights, dim3(192), dim3(256), 0, stream,
                       W_merge, W_ms, W_msamp, (__hip_bfloat16*)d_ws);

    hipLaunchKernelGGL(encoder_fused, dim3(2048), dim3(256), 0, stream,
                       last, sample, child_l, child_r, child_s,
                       (const __bf16*)d_ws,
                       b_merge, a_merge, b_ms, a_ms, b_msamp, a_msamp, out);
}

// Round 9
// 234.452 us; speedup vs baseline: 1.0621x; 1.0577x over previous
//
#include <hip/hip_runtime.h>
#include <hip/hip_bf16.h>

#define N_TOT 65536
#define M_TOT 32768

typedef __bf16  bf16x8 __attribute__((ext_vector_type(8)));
typedef __bf16  bf16x4 __attribute__((ext_vector_type(4)));
typedef float   f32x4  __attribute__((ext_vector_type(4)));
typedef uint32_t u32x2 __attribute__((ext_vector_type(2)));
typedef bf16x8 bf16x8_a __attribute__((may_alias));
typedef u32x2  u32x2_a  __attribute__((may_alias));

__device__ __forceinline__ float prelu_f(float x, float a) { return x >= 0.f ? x : a * x; }
// s'-tile swizzle (R1/R7-verified): XOR 16B-slot index with ((row^(row>>3))&7)
__device__ __forceinline__ int swzf(int row) { return ((row ^ (row >> 3)) & 7) << 4; }

__device__ __forceinline__ bf16x8 cvt8(f32x4 a, f32x4 b) {
    bf16x8 v;
    v[0] = (__bf16)a[0]; v[1] = (__bf16)a[1]; v[2] = (__bf16)a[2]; v[3] = (__bf16)a[3];
    v[4] = (__bf16)b[0]; v[5] = (__bf16)b[1]; v[6] = (__bf16)b[2]; v[7] = (__bf16)b[3];
    return v;
}

#define MFMA(A, B, C) __builtin_amdgcn_mfma_f32_16x16x32_bf16((A), (B), (C), 0, 0, 0)

// d_ws layout (bf16): [0,8192) Wm_t[64][128]; [8192,40960) Wms_t[256][128];
// [40960,49152) Wsa_t[64][128].  Wm_t/Wms_t[n][k] = W[k][n].
// Wsa_t is k-PERMUTED on its ans half: Wsa_t[n][s] = W_msamp[f(s)][n] where
// for s<64: g=(s>>3)&3, kk=s>>5, e=s&7, f = (kk*2+(e>>2))*16 + g*4 + (e&3);
// for s>=64: f=s. This aligns stage-1's D-fragment layout with stage-3's
// B-fragment layout so ans needs NO cross-lane exchange at all (the R2-R7
// shuffle network -- whose lane-varying selects between array elements forced
// the frame into scratch, VGPR 44 + 73MB spill writes -- is deleted, as is
// R8's racy LDS exchange).
__global__ void prep_weights(const float* __restrict__ Wm,
                             const float* __restrict__ Wms,
                             const float* __restrict__ Wsa,
                             __hip_bfloat16* __restrict__ ws)
{
    int t = blockIdx.x * blockDim.x + threadIdx.x;
    if (t < 8192) {
        int n = t >> 7, k = t & 127;
        ws[t] = __float2bfloat16(Wm[k * 64 + n]);
    } else if (t < 40960) {
        int u = t - 8192; int n = u >> 7, k = u & 127;
        ws[t] = __float2bfloat16(Wms[k * 256 + n]);
    } else if (t < 49152) {
        int u = t - 40960; int n = u >> 7, s = u & 127;
        int f;
        if (s < 64) {
            const int g  = (s >> 3) & 3;
            const int kk = s >> 5;
            const int e  = s & 7;
            f = (kk * 2 + (e >> 2)) * 16 + g * 4 + (e & 3);
        } else {
            f = s;
        }
        ws[t] = __float2bfloat16(Wsa[f * 64 + n]);
    }
}

// One wave = 16 nodes, fused stage1/2/3. s' via 8KB/wave LDS (R7 text);
// ans stays IN-LANE thanks to the Wsa k-permutation (see prep_weights).
// Swapped MFMA throughout: D = W^T X^T.
__global__ __launch_bounds__(256, 2) void encoder_fused(
    const float* __restrict__ last,
    const float* __restrict__ sample,
    const int* __restrict__ child_l,
    const int* __restrict__ child_r,
    const int* __restrict__ child_s,
    const __bf16* __restrict__ wt,
    const float* __restrict__ b_merge, const float* __restrict__ a_merge_p,
    const float* __restrict__ b_ms,    const float* __restrict__ a_ms_p,
    const float* __restrict__ b_msamp, const float* __restrict__ a_msamp_p,
    float* __restrict__ out)
{
    __shared__ char lds_raw[4][8192];       // 32KB/block
    const int tid  = threadIdx.x;
    const int lane = tid & 63;
    const int wid  = tid >> 6;
    char* Y = &lds_raw[wid][0];             // wave-private [64 rows][128B]

    const int group  = blockIdx.x * 4 + wid;
    const int b      = group >> 11;
    const int m_base = (group & 2047) << 4;

    const int g   = lane >> 4;
    const int j15 = lane & 15;
    const int nl  = j15 >> 2;
    const int c   = j15 & 3;

    const float a_merge = *a_merge_p;
    const float a_ms    = *a_ms_p;
    const float a_msamp = *a_msamp_p;

    const __bf16* Wm_t  = wt;
    const __bf16* Wms_t = wt + 8192;
    const __bf16* Wsa_t = wt + 40960;

    // ---- stage 2: s' = prelu(s @ W_ms + b_ms) -> LDS (R7 text) ----
    {
        const int cs = child_s[m_base + j15];
        const float* ssrc = sample + ((size_t)(b * N_TOT + cs)) * 128;
        bf16x8 sf[4];
#pragma unroll
        for (int kk = 0; kk < 4; ++kk) {
            f32x4 f0 = *(const f32x4*)(ssrc + kk * 32 + g * 8);
            f32x4 f1 = *(const f32x4*)(ssrc + kk * 32 + g * 8 + 4);
            sf[kk] = cvt8(f0, f1);
        }
#pragma unroll
        for (int n2 = 0; n2 < 16; ++n2) {
            f32x4 acc = {0.f, 0.f, 0.f, 0.f};
#pragma unroll
            for (int kk = 0; kk < 4; ++kk) {
                bf16x8 w = *(const bf16x8*)(Wms_t + (n2 * 16 + j15) * 128 + kk * 32 + g * 8);
                acc = MFMA(w, sf[kk], acc);
            }
            f32x4 bb = *(const f32x4*)(b_ms + n2 * 16 + g * 4);
            bf16x4 ph;
            ph[0] = (__bf16)prelu_f(acc[0] + bb[0], a_ms);
            ph[1] = (__bf16)prelu_f(acc[1] + bb[1], a_ms);
            ph[2] = (__bf16)prelu_f(acc[2] + bb[2], a_ms);
            ph[3] = (__bf16)prelu_f(acc[3] + bb[3], a_ms);
            const int row = j15 * 4 + (n2 >> 2);          // node j15, c = n2>>2
            const int d   = (n2 & 3) * 16 + g * 4;        // within-c feature
            *(u32x2_a*)(Y + row * 128 + ((2 * d) ^ swzf(row))) = __builtin_bit_cast(u32x2, ph);
        }
    }
    // compiler-level fence: Y writes above are read cross-lane in stage 3;
    // forbid any load/store reordering across this point (R8 lesson: per-lane
    // alias analysis would otherwise allow hoisting LDS reads over the writes).
    asm volatile("" ::: "memory");

    // ---- fused stage 1 + stage 3, per t (no exchange needed) ----
#pragma unroll
    for (int t = 0; t < 4; ++t) {
        const int m  = m_base + t * 4 + nl;
        const int cl = child_l[m];
        const int cr = child_r[m];
        const float* lsrc = last + ((size_t)((b * N_TOT + cl) * 4 + c)) * 64;
        const float* rsrc = last + ((size_t)((b * N_TOT + cr) * 4 + c)) * 64;

        bf16x8 xf[4];
#pragma unroll
        for (int kk = 0; kk < 4; ++kk) {
            const int k = kk * 32 + g * 8;       // k<64 -> lch, else rch
            const float* src = (k < 64) ? (lsrc + k) : (rsrc + (k - 64));
            f32x4 f0 = *(const f32x4*)(src);
            f32x4 f1 = *(const f32x4*)(src + 4);
            xf[kk] = cvt8(f0, f1);
        }

        // stage-1 MFMA: lane (g,j15) produces ans feats n*16+g*4..+3 for row
        // 16t+j15. Under the Wsa k-permutation these 16 values are EXACTLY
        // this lane's stage-3 B-fragment slots: yf0 = (n=0 | n=1), yf1 = (n=2 | n=3).
        f32x4 pp[4];
#pragma unroll
        for (int n = 0; n < 4; ++n) {
            f32x4 acc = {0.f, 0.f, 0.f, 0.f};
#pragma unroll
            for (int kk = 0; kk < 4; ++kk) {
                bf16x8 w = *(const bf16x8*)(Wm_t + (n * 16 + j15) * 128 + kk * 32 + g * 8);
                acc = MFMA(w, xf[kk], acc);
            }
            f32x4 bm = *(const f32x4*)(b_merge + n * 16 + g * 4);
            f32x4 p;
            p[0] = prelu_f(acc[0] + bm[0], a_merge);
            p[1] = prelu_f(acc[1] + bm[1], a_merge);
            p[2] = prelu_f(acc[2] + bm[2], a_merge);
            p[3] = prelu_f(acc[3] + bm[3], a_merge);
            pp[n] = p;
        }
        bf16x8 yf0 = cvt8(pp[0], pp[1]);
        bf16x8 yf1 = cvt8(pp[2], pp[3]);

        // s' fragments from LDS (R7 text)
        const int row = t * 16 + j15;
        const int sz  = swzf(row);
        bf16x8 yf2 = *(const bf16x8_a*)(Y + row * 128 + ((16 * g) ^ sz));
        bf16x8 yf3 = *(const bf16x8_a*)(Y + row * 128 + ((64 + 16 * g) ^ sz));

        // stage 3: out = prelu([ans|s'] @ W_msamp + b_msamp), Wsa_t k-permuted
        float* obase = out + ((size_t)((b * M_TOT + m_base + t * 4 + nl) * 4 + c)) * 64;
#pragma unroll
        for (int n = 0; n < 4; ++n) {
            f32x4 acc = {0.f, 0.f, 0.f, 0.f};
            bf16x8 w0 = *(const bf16x8*)(Wsa_t + (n * 16 + j15) * 128 + 0 * 32 + g * 8);
            bf16x8 w1 = *(const bf16x8*)(Wsa_t + (n * 16 + j15) * 128 + 1 * 32 + g * 8);
            bf16x8 w2 = *(const bf16x8*)(Wsa_t + (n * 16 + j15) * 128 + 2 * 32 + g * 8);
            bf16x8 w3 = *(const bf16x8*)(Wsa_t + (n * 16 + j15) * 128 + 3 * 32 + g * 8);
            acc = MFMA(w0, yf0, acc);
            acc = MFMA(w1, yf1, acc);
            acc = MFMA(w2, yf2, acc);
            acc = MFMA(w3, yf3, acc);
            f32x4 ba = *(const f32x4*)(b_msamp + n * 16 + g * 4);
            f32x4 o;
            o[0] = prelu_f(acc[0] + ba[0], a_msamp);
            o[1] = prelu_f(acc[1] + ba[1], a_msamp);
            o[2] = prelu_f(acc[2] + ba[2], a_msamp);
            o[3] = prelu_f(acc[3] + ba[3], a_msamp);
            // streamed output, never re-read: non-temporal to keep L2/L3 for gathers
            __builtin_nontemporal_store(o, (f32x4*)(obase + n * 16 + g * 4));
        }
    }
}

extern "C" void kernel_launch(void* const* d_in, const int* in_sizes, int n_in,
                              void* d_out, int out_size, void* d_ws, size_t ws_size,
                              hipStream_t stream)
{
    const float* last    = (const float*)d_in[0];
    const float* sample  = (const float*)d_in[1];
    const int*   child_l = (const int*)d_in[2];
    const int*   child_r = (const int*)d_in[3];
    const int*   child_s = (const int*)d_in[4];
    const float* W_merge = (const float*)d_in[5];
    const float* b_merge = (const float*)d_in[6];
    const float* a_merge = (const float*)d_in[7];
    const float* W_ms    = (const float*)d_in[8];
    const float* b_ms    = (const float*)d_in[9];
    const float* a_ms    = (const float*)d_in[10];
    const float* W_msamp = (const float*)d_in[11];
    const float* b_msamp = (const float*)d_in[12];
    const float* a_msamp = (const float*)d_in[13];
    float* out = (float*)d_out;

    hipLaunchKernelGGL(prep_weights, dim3(192), dim3(256), 0, stream,
                       W_merge, W_ms, W_msamp, (__hip_bfloat16*)d_ws);

    hipLaunchKernelGGL(encoder_fused, dim3(2048), dim3(256), 0, stream,
                       last, sample, child_l, child_r, child_s,
                       (const __bf16*)d_ws,
                       b_merge, a_merge, b_ms, a_ms, b_msamp, a_msamp, out);
}